// Round 2
// baseline (2704.476 us; speedup 1.0000x reference)
//
#include <hip/hip_runtime.h>
#include <hip/hip_bf16.h>

#define LDSK 136  // padded LDS row stride (elements) for transposed weight tile

typedef __bf16 bf16x8_t __attribute__((ext_vector_type(8)));
typedef float  f32x4_t  __attribute__((ext_vector_type(4)));

__device__ __forceinline__ float gelu_f(float x) {
    return 0.5f * x * (1.0f + erff(x * 0.70710678118654752440f));
}

// Stage W[128][128] fp32 (row-major, x@W) transposed into LDS as bf16:
// Wt[n][k], row stride LDSK. Also stage fp32 bias.
__device__ __forceinline__ void stage_w_bias(const float* __restrict__ W,
                                             const float* __restrict__ bvec,
                                             __bf16* Wt, float* bias_s) {
    for (int i = threadIdx.x * 8; i < 128 * 128; i += 256 * 8) {
        int k = i >> 7, n = i & 127;
        f32x4_t v0 = *(const f32x4_t*)(W + i);
        f32x4_t v1 = *(const f32x4_t*)(W + i + 4);
        #pragma unroll
        for (int j = 0; j < 4; ++j) {
            Wt[(n + j) * LDSK + k]     = (__bf16)v0[j];
            Wt[(n + 4 + j) * LDSK + k] = (__bf16)v1[j];
        }
    }
    if (threadIdx.x < 128) bias_s[threadIdx.x] = bvec[threadIdx.x];
}

// OUT[row] = (accum?OUT:0) + op( (A*ascale) @ W + bias + (ADD?ADD:0) ), op=gelu if do_gelu
__global__ __launch_bounds__(256) void k_node_gemm(
    const float* __restrict__ A, int M,
    const float* __restrict__ W, const float* __restrict__ bvec,
    const float* __restrict__ eps_elem,
    const float* __restrict__ ADD, float* __restrict__ OUT,
    int do_gelu, int accum)
{
    __shared__ __bf16 Wt[128 * LDSK];
    __shared__ float bias_s[128];
    stage_w_bias(W, bvec, Wt, bias_s);
    __syncthreads();

    int lane = threadIdx.x & 63, wave = threadIdx.x >> 6;
    int q = lane >> 4, c = lane & 15;
    int m0 = blockIdx.x * 64 + wave * 16;

    float ascale = 1.0f;
    if (eps_elem) ascale = 1.0f + *eps_elem;

    int arow = m0 + c;
    bf16x8_t afr[4];
    if (arow < M) {
        const float* ap = A + (size_t)arow * 128;
        #pragma unroll
        for (int kb = 0; kb < 4; ++kb) {
            const float* p = ap + kb * 32 + q * 8;
            f32x4_t x0 = *(const f32x4_t*)p;
            f32x4_t x1 = *(const f32x4_t*)(p + 4);
            bf16x8_t v;
            #pragma unroll
            for (int j = 0; j < 4; ++j) {
                v[j]     = (__bf16)(x0[j] * ascale);
                v[j + 4] = (__bf16)(x1[j] * ascale);
            }
            afr[kb] = v;
        }
    } else {
        #pragma unroll
        for (int kb = 0; kb < 4; ++kb) {
            bf16x8_t z;
            #pragma unroll
            for (int j = 0; j < 8; ++j) z[j] = (__bf16)0.0f;
            afr[kb] = z;
        }
    }

    #pragma unroll
    for (int nt = 0; nt < 8; ++nt) {
        f32x4_t acc = {0.f, 0.f, 0.f, 0.f};
        #pragma unroll
        for (int kb = 0; kb < 4; ++kb) {
            bf16x8_t b = *(const bf16x8_t*)&Wt[(nt * 16 + c) * LDSK + kb * 32 + q * 8];
            acc = __builtin_amdgcn_mfma_f32_16x16x32_bf16(afr[kb], b, acc, 0, 0, 0);
        }
        int col = nt * 16 + c;
        #pragma unroll
        for (int r = 0; r < 4; ++r) {
            int rowg = m0 + q * 4 + r;
            if (rowg < M) {
                size_t o = (size_t)rowg * 128 + col;
                float v = acc[r] + bias_s[col];
                if (ADD) v += ADD[o];
                if (do_gelu) v = gelu_f(v);
                if (accum) v += OUT[o];
                OUT[o] = v;
            }
        }
    }
}

// Fused: e = ea@We + be ; m = gelu(XS[src] + e) * ew ; atomicAdd(AGG[dst], m)
// E must be a multiple of 64 (true for all 4 edge types).
__global__ __launch_bounds__(256) void k_edge(
    const float* __restrict__ ea,
    const int* __restrict__ esrc, const int* __restrict__ edst,
    const float* __restrict__ ew, int E,
    const float* __restrict__ W, const float* __restrict__ bvec,
    const float* __restrict__ XS, float* __restrict__ AGG)
{
    __shared__ __bf16 Wt[128 * LDSK];
    __shared__ float bias_s[128];
    stage_w_bias(W, bvec, Wt, bias_s);
    __syncthreads();

    int lane = threadIdx.x & 63, wave = threadIdx.x >> 6;
    int q = lane >> 4, c = lane & 15;
    int m0 = blockIdx.x * 64 + wave * 16;

    const float* ap = ea + (size_t)(m0 + c) * 128;
    bf16x8_t afr[4];
    #pragma unroll
    for (int kb = 0; kb < 4; ++kb) {
        const float* p = ap + kb * 32 + q * 8;
        f32x4_t x0 = *(const f32x4_t*)p;
        f32x4_t x1 = *(const f32x4_t*)(p + 4);
        bf16x8_t v;
        #pragma unroll
        for (int j = 0; j < 4; ++j) {
            v[j]     = (__bf16)x0[j];
            v[j + 4] = (__bf16)x1[j];
        }
        afr[kb] = v;
    }

    int se[4], de[4];
    float wv[4];
    #pragma unroll
    for (int r = 0; r < 4; ++r) {
        int e = m0 + q * 4 + r;
        se[r] = esrc[e];
        de[r] = edst[e];
        wv[r] = ew[e];
    }

    #pragma unroll
    for (int nt = 0; nt < 8; ++nt) {
        f32x4_t acc = {0.f, 0.f, 0.f, 0.f};
        #pragma unroll
        for (int kb = 0; kb < 4; ++kb) {
            bf16x8_t b = *(const bf16x8_t*)&Wt[(nt * 16 + c) * LDSK + kb * 32 + q * 8];
            acc = __builtin_amdgcn_mfma_f32_16x16x32_bf16(afr[kb], b, acc, 0, 0, 0);
        }
        int col = nt * 16 + c;
        #pragma unroll
        for (int r = 0; r < 4; ++r) {
            float v = acc[r] + bias_s[col] + XS[(size_t)se[r] * 128 + col];
            v = gelu_f(v) * wv[r];
            atomicAdd(&AGG[(size_t)de[r] * 128 + col], v);
        }
    }
}

__global__ void k_copy(const float* __restrict__ in, float* __restrict__ out, int n) {
    int i = blockIdx.x * 256 + threadIdx.x;
    if (i < n) out[i] = in[i];
}

__global__ void k_zero(float* __restrict__ p, int n) {
    int i = blockIdx.x * 256 + threadIdx.x;
    if (i < n) p[i] = 0.0f;
}

__global__ void k_residual(float* __restrict__ X, const float* __restrict__ O, int n) {
    int i = blockIdx.x * 256 + threadIdx.x;
    if (i < n) X[i] += gelu_f(O[i]);
}

__global__ void k_store(const float* __restrict__ XB, const float* __restrict__ XC,
                        float* __restrict__ out, int nb, int nc) {
    int i = blockIdx.x * 256 + threadIdx.x;
    if (i < nb) out[i] = XB[i];
    else if (i < nb + nc) out[i] = XC[i - nb];
}

extern "C" void kernel_launch(void* const* d_in, const int* in_sizes, int n_in,
                              void* d_out, int out_size, void* d_ws, size_t ws_size,
                              hipStream_t stream)
{
    const float* xb_in = (const float*)d_in[0];
    const float* xc_in = (const float*)d_in[1];
    const int NB = in_sizes[0] / 128;
    const int NC = in_sizes[1] / 128;

    // edge-type order t: 0=bb 1=bc 2=cc 3=cb ; input slots: bb@2, bc@5, cc@8, cb@11
    const int slot[4] = {2, 5, 8, 11};
    const int* ei_[4]; const float *ea_[4], *ew_[4]; int E_[4];
    for (int t = 0; t < 4; ++t) {
        ei_[t] = (const int*)d_in[slot[t]];
        ea_[t] = (const float*)d_in[slot[t] + 1];
        ew_[t] = (const float*)d_in[slot[t] + 2];
        E_[t]  = in_sizes[slot[t]] / 2;
    }
    const float* Wsrc = (const float*)d_in[14];
    const float* bsrc = (const float*)d_in[15];
    const float* Wdst = (const float*)d_in[16];
    const float* bdst = (const float*)d_in[17];
    const float* epsp = (const float*)d_in[18];
    const float* Wep  = (const float*)d_in[19];
    const float* bep  = (const float*)d_in[20];
    const float* Wm1  = (const float*)d_in[21];
    const float* bm1  = (const float*)d_in[22];
    const float* Wm2  = (const float*)d_in[23];
    const float* bm2  = (const float*)d_in[24];

    // fp32 workspace layout (~105 MB): T aliases AGG (AGG fully consumed by
    // the lin_dst pass before the MLP hidden overwrites it).
    float* XB  = (float*)d_ws;                 // [NB,128] current base features
    float* XC  = XB  + (size_t)NB * 128;       // [NC,128]
    float* XS  = XC  + (size_t)NC * 128;       // [NB,128] lin_src out, then H
    float* AGG = XS  + (size_t)NB * 128;       // [NB,128] segment-sum, then MLP hidden
    float* T   = AGG;
    float* OB  = AGG + (size_t)NB * 128;       // [NB,128] conv-sum for base
    float* OC  = OB  + (size_t)NB * 128;       // [NC,128] conv-sum for cent

    dim3 blk(256);
    k_copy<<<dim3((NB * 128 + 255) / 256), blk, 0, stream>>>(xb_in, XB, NB * 128);
    k_copy<<<dim3((NC * 128 + 255) / 256), blk, 0, stream>>>(xc_in, XC, NC * 128);

    const int tlist[4] = {0, 3, 1, 2};  // bb, cb -> OB ; bc, cc -> OC
    for (int l = 0; l < 2; ++l) {
        for (int bi = 0; bi < 4; ++bi) {
            int t = tlist[bi];
            const float* srcx = (t == 0 || t == 1) ? XB : XC;
            int ns            = (t == 0 || t == 1) ? NB : NC;
            const float* dstx = (t == 0 || t == 3) ? XB : XC;
            int nd            = (t == 0 || t == 3) ? NB : NC;
            float* outp       = (t == 0 || t == 3) ? OB : OC;
            int accum         = (bi == 1 || bi == 3);
            size_t pi = (size_t)(l * 4 + t);

            // xs = x_src @ Wsrc + bsrc
            k_node_gemm<<<dim3((ns + 63) / 64), blk, 0, stream>>>(
                srcx, ns, Wsrc + pi * 16384, bsrc + pi * 128,
                nullptr, nullptr, XS, 0, 0);
            // agg = 0
            int nz = nd * 128;
            k_zero<<<dim3((nz + 255) / 256), blk, 0, stream>>>(AGG, nz);
            // agg += scatter(gelu(xs[src] + ea@We + be) * ew)
            int E = E_[t];
            k_edge<<<dim3(E / 64), blk, 0, stream>>>(
                ea_[t], ei_[t], ei_[t] + E, ew_[t], E,
                Wep + pi * 16384, bep + pi * 128, XS, AGG);
            // H = agg + ((1+eps)*x_dst) @ Wd + bd   (H overwrites XS)
            k_node_gemm<<<dim3((nd + 63) / 64), blk, 0, stream>>>(
                dstx, nd, Wdst + pi * 16384, bdst + pi * 128,
                epsp + pi, AGG, XS, 0, 0);
            // T = gelu(H @ W1 + b1)   (T aliases AGG, AGG already consumed)
            k_node_gemm<<<dim3((nd + 63) / 64), blk, 0, stream>>>(
                XS, nd, Wm1 + pi * 16384, bm1 + pi * 128,
                nullptr, nullptr, T, 1, 0);
            // out (+)= T @ W2 + b2
            k_node_gemm<<<dim3((nd + 63) / 64), blk, 0, stream>>>(
                T, nd, Wm2 + pi * 16384, bm2 + pi * 128,
                nullptr, nullptr, outp, 0, accum);
        }
        k_residual<<<dim3((NB * 128 + 255) / 256), blk, 0, stream>>>(XB, OB, NB * 128);
        k_residual<<<dim3((NC * 128 + 255) / 256), blk, 0, stream>>>(XC, OC, NC * 128);
    }
    k_store<<<dim3((out_size + 255) / 256), blk, 0, stream>>>(
        XB, XC, (float*)d_out, NB * 128, NC * 128);
}